// Round 1
// baseline (120.449 us; speedup 1.0000x reference)
//
#include <hip/hip_runtime.h>

// Exact floor(log2(x)) for x > 0, including denormals.
__device__ __forceinline__ int flog2_exact(float x) {
    unsigned b = __float_as_uint(x);
    int e = (int)((b >> 23) & 0xFFu);
    if (e == 0) {                       // denormal: x = m * 2^-149
        unsigned m = b & 0x7FFFFFu;
        return 31 - __clz(m) - 149;     // floor(log2(m)) - 149
    }
    return e - 127;
}

// sign(v) * floor(|v| + 0.5), same fp32 ops as the reference
__device__ __forceinline__ float round_ref(float v) {
    return copysignf(floorf(fabsf(v) + 0.5f), v);
}

__global__ __launch_bounds__(256) void mxq_kernel(const float* __restrict__ x,
                                                  float* __restrict__ y,
                                                  int nblk) {
    const int lane = threadIdx.x & 63;
    const int wid  = blockIdx.x * (blockDim.x >> 6) + (threadIdx.x >> 6);
    const int nw   = gridDim.x * (blockDim.x >> 6);

    for (int b = wid; b < nblk; b += nw) {
        const float2 v = reinterpret_cast<const float2*>(x)[(size_t)b * 64 + lane];
        float a0 = v.x, a1 = v.y;
        float ab0 = fabsf(a0), ab1 = fabsf(a1);

        // ---- mean of |A| (fp64 reduction) ----
        double s = (double)ab0 + (double)ab1;
        #pragma unroll
        for (int off = 1; off < 64; off <<= 1) s += __shfl_xor(s, off);
        double mean = s * (1.0 / 128.0);

        // ---- population std of |A| (two-pass, fp64) ----
        double d0 = (double)ab0 - mean, d1 = (double)ab1 - mean;
        double s2 = d0 * d0 + d1 * d1;
        #pragma unroll
        for (int off = 1; off < 64; off <<= 1) s2 += __shfl_xor(s2, off);
        double stdv = sqrt(s2 * (1.0 / 128.0));

        double lo = mean - 2.0 * stdv;
        double hi = mean + 2.0 * stdv;
        bool o0 = ((double)a0 < lo) || ((double)a0 > hi);
        bool o1 = ((double)a1 < lo) || ((double)a1 > hi);

        float in0 = o0 ? 0.0f : a0, in1 = o1 ? 0.0f : a1;
        float ov0 = o0 ? a0 : 0.0f, ov1 = o1 ? a1 : 0.0f;

        // ---- inlier shared exponent ----
        float mi = fmaxf(fabsf(in0), fabsf(in1));
        #pragma unroll
        for (int off = 1; off < 64; off <<= 1) mi = fmaxf(mi, __shfl_xor(mi, off));
        int se_in = (mi == 0.0f) ? -126 : flog2_exact(mi);   // EMAX_IN = 0
        if (se_in < -127) se_in = -20;                       // SCALE_LO
        float s_in  = ldexpf(1.0f, se_in);
        float rs_in = ldexpf(1.0f, -se_in);

        // ---- inlier quantize: ebits=0, scale = 2^(6-2) = 16, clip +-31/16 ----
        float t0 = in0 * rs_in, t1 = in1 * rs_in;
        float q0 = round_ref(t0 * 16.0f) * 0.0625f;
        float q1 = round_ref(t1 * 16.0f) * 0.0625f;
        q0 = fminf(fmaxf(q0, -1.9375f), 1.9375f) * s_in;
        q1 = fminf(fmaxf(q1, -1.9375f), 1.9375f) * s_in;

        // ---- outlier path: scaled UP by s_in ----
        float w0 = ov0 * s_in, w1 = ov1 * s_in;
        float mo = fmaxf(fabsf(w0), fabsf(w1));
        #pragma unroll
        for (int off = 1; off < 64; off <<= 1) mo = fmaxf(mo, __shfl_xor(mo, off));
        int se_out = ((mo == 0.0f) ? -126 : flog2_exact(mo)) - 8;  // EMAX_OUT = 8
        if (se_out < -127) se_out = -20;
        float s_out  = ldexpf(1.0f, se_out);
        float rs_out = ldexpf(1.0f, -se_out);

        // ---- outlier quantize: ebits=4, mbits=5, clip +-448 ----
        float u0 = w0 * rs_out, u1 = w1 * rs_out;
        int p0 = (u0 == 0.0f) ? 0 : flog2_exact(fabsf(u0));
        int p1 = (u1 == 0.0f) ? 0 : flog2_exact(fabsf(u1));
        p0 = max(p0, -6); p1 = max(p1, -6);
        float r0 = round_ref(u0 * ldexpf(1.0f, 3 - p0)) * ldexpf(1.0f, p0 - 3);
        float r1 = round_ref(u1 * ldexpf(1.0f, 3 - p1)) * ldexpf(1.0f, p1 - 3);
        r0 = fminf(fmaxf(r0, -448.0f), 448.0f);
        r1 = fminf(fmaxf(r1, -448.0f), 448.0f);
        float oq0 = (r0 * s_out) * rs_in;
        float oq1 = (r1 * s_out) * rs_in;

        float2 res;
        res.x = q0 + oq0;
        res.y = q1 + oq1;
        reinterpret_cast<float2*>(y)[(size_t)b * 64 + lane] = res;
    }
}

extern "C" void kernel_launch(void* const* d_in, const int* in_sizes, int n_in,
                              void* d_out, int out_size, void* d_ws, size_t ws_size,
                              hipStream_t stream) {
    const float* x = (const float*)d_in[0];
    float* y = (float*)d_out;
    int n = in_sizes[0];
    int nblk = n / 128;                 // 262144 blocks of 128
    int threads = 256;
    int waves_per_wg = threads / 64;
    int grid = 2048;                    // 8 wg/CU, grid-stride over blocks
    int max_grid = (nblk + waves_per_wg - 1) / waves_per_wg;
    if (grid > max_grid) grid = max_grid;
    mxq_kernel<<<grid, threads, 0, stream>>>(x, y, nblk);
}

// Round 3
// 61.569 us; speedup vs baseline: 1.9563x; 1.9563x over previous
//
#include <hip/hip_runtime.h>

typedef float f32x4 __attribute__((ext_vector_type(4)));

// Exact floor(log2(x)) for x > 0, including denormals (used on block maxima only).
__device__ __forceinline__ int flog2_exact(float x) {
    unsigned b = __float_as_uint(x);
    int e = (int)((b >> 23) & 0xFFu);
    if (e == 0) {                       // denormal: x = m * 2^-149
        unsigned m = b & 0x7FFFFFu;
        return 31 - __clz(m) - 149;
    }
    return e - 127;
}

// sign(v) * floor(|v| + 0.5) — same fp32 ops as the reference
__device__ __forceinline__ float round_ref(float v) {
    return copysignf(floorf(fabsf(v) + 0.5f), v);
}

__global__ __launch_bounds__(256) void mxq_kernel(const f32x4* __restrict__ x,
                                                  f32x4* __restrict__ y,
                                                  int npair) {  // npair = nblk/2
    const int lane = threadIdx.x & 63;
    const int wid  = blockIdx.x * (blockDim.x >> 6) + (threadIdx.x >> 6);
    const int nw   = gridDim.x * (blockDim.x >> 6);

    for (int p = wid; p < npair; p += nw) {
        // wave covers 2 consecutive 128-elem blocks; lanes 0-31 = block 2p,
        // lanes 32-63 = block 2p+1. float4 index p*64+lane is exactly that.
        const f32x4 v = x[(size_t)p * 64 + lane];
        float a[4] = {v.x, v.y, v.z, v.w};
        float ab[4];

        // ---- one-pass fp64 stats: sum|a|, sum a^2 ----
        double s = 0.0, s2 = 0.0;
        #pragma unroll
        for (int i = 0; i < 4; ++i) {
            ab[i] = fabsf(a[i]);
            double d = (double)ab[i];
            s += d;
            s2 = fma(d, d, s2);
        }
        #pragma unroll
        for (int off = 1; off < 32; off <<= 1) {   // half-wave reduce (per block)
            s  += __shfl_xor(s, off);
            s2 += __shfl_xor(s2, off);
        }
        double mean = s * (1.0 / 128.0);
        double var  = fma(mean, -mean, s2 * (1.0 / 128.0));
        var = var < 0.0 ? 0.0 : var;
        double stdv = sqrt(var);
        double lo = mean - 2.0 * stdv;
        double hi = mean + 2.0 * stdv;

        // ---- classify + lane-local maxima ----
        float inl[4], ov[4];
        float mi = 0.0f, mov = 0.0f;
        #pragma unroll
        for (int i = 0; i < 4; ++i) {
            double ad = (double)a[i];
            bool o = (ad < lo) || (ad > hi);
            inl[i] = o ? 0.0f : a[i];
            ov[i]  = a[i] - inl[i];               // exact: a or 0
            mi  = fmaxf(mi,  o ? 0.0f : ab[i]);
            mov = fmaxf(mov, o ? ab[i] : 0.0f);
        }
        #pragma unroll
        for (int off = 1; off < 32; off <<= 1) {
            mi  = fmaxf(mi,  __shfl_xor(mi, off));
            mov = fmaxf(mov, __shfl_xor(mov, off));
        }

        // ---- shared exponents (exact integer math) ----
        int se_in = (mi == 0.0f) ? -126 : flog2_exact(mi);       // EMAX_IN = 0
        if (se_in < -127) se_in = -20;                           // SCALE_LO
        // max|outlier*s_in| = mov * 2^se_in  ->  flog2 = flog2(mov) + se_in
        int se_out = ((mov == 0.0f) ? -126 : (flog2_exact(mov) + se_in)) - 8;
        if (se_out < -127) se_out = -20;
        const int k1 = se_in - se_out;

        // ---- quantize ----
        f32x4 res;
        #pragma unroll
        for (int i = 0; i < 4; ++i) {
            // inlier: ebits=0, scale=16, clip +-31/16 (folded into integer clamp)
            float r = round_ref(ldexpf(inl[i], 4 - se_in));
            r = fminf(fmaxf(r, -31.0f), 31.0f);
            float q = ldexpf(r, se_in - 4);
            // outlier: u = ov * s_in / s_out (exact single ldexp)
            float u = ldexpf(ov[i], k1);
            int pe = (int)((__float_as_uint(u) >> 23) & 0xFFu) - 127; // denorm->-127->clamp
            pe = pe < -6 ? -6 : pe;                                   // emin = -2^(4-1)+2
            float rr = round_ref(ldexpf(u, 3 - pe));
            float vq = ldexpf(rr, pe - 3);
            vq = fminf(fmaxf(vq, -448.0f), 448.0f);
            float oq = ldexpf(vq, -k1);              // * s_out / s_in (exact)
            res[i] = q + oq;
        }

        __builtin_nontemporal_store(res, &y[(size_t)p * 64 + lane]);
    }
}

extern "C" void kernel_launch(void* const* d_in, const int* in_sizes, int n_in,
                              void* d_out, int out_size, void* d_ws, size_t ws_size,
                              hipStream_t stream) {
    const f32x4* x = (const f32x4*)d_in[0];
    f32x4* y = (f32x4*)d_out;
    int n = in_sizes[0];
    int npair = n / 256;                 // 131072 wave-tasks (2 blocks each)
    int threads = 256;
    int waves_per_wg = threads / 64;
    int grid = 2048;                     // fills 8192 wave slots; grid-stride
    int max_grid = (npair + waves_per_wg - 1) / waves_per_wg;
    if (grid > max_grid) grid = max_grid;
    mxq_kernel<<<grid, threads, 0, stream>>>(x, y, npair);
}

// Round 4
// 46.069 us; speedup vs baseline: 2.6146x; 1.3365x over previous
//
#include <hip/hip_runtime.h>

typedef float f32x4 __attribute__((ext_vector_type(4)));

// Exact floor(log2(x)) for x > 0, including denormals (used on block maxima only).
__device__ __forceinline__ int flog2_exact(float x) {
    unsigned b = __float_as_uint(x);
    int e = (int)((b >> 23) & 0xFFu);
    if (e == 0) {                       // denormal
        unsigned m = b & 0x7FFFFFu;
        return 31 - __clz(m) - 149;
    }
    return e - 127;
}

// sign(v) * floor(|v| + 0.5) — same fp32 ops as the reference
__device__ __forceinline__ float round_ref(float v) {
    return copysignf(floorf(fabsf(v) + 0.5f), v);
}

__global__ __launch_bounds__(256) void mxq_kernel(const f32x4* __restrict__ x,
                                                  f32x4* __restrict__ y,
                                                  int ntask) {  // task = 4 blocks = 512 elems
    const int lane = threadIdx.x & 63;
    const int l    = lane & 15;       // lane within 16-lane block group
    const int q    = lane >> 4;       // which of the wave's 4 blocks
    const int wid  = blockIdx.x * (blockDim.x >> 6) + (threadIdx.x >> 6);
    const int nw   = gridDim.x * (blockDim.x >> 6);

    for (int t = wid; t < ntask; t += nw) {
        const size_t base = (size_t)t * 128 + q * 32 + l;
        const f32x4 v0 = x[base];
        const f32x4 v1 = x[base + 16];
        float a[8] = {v0.x, v0.y, v0.z, v0.w, v1.x, v1.y, v1.z, v1.w};

        // ---- one-pass fp64 stats over the 16-lane group (one 128-elem block) ----
        double s = 0.0, s2 = 0.0;
        #pragma unroll
        for (int i = 0; i < 8; ++i) {
            double d = (double)fabsf(a[i]);
            s += d;
            s2 = fma(d, d, s2);
        }
        #pragma unroll
        for (int off = 1; off < 16; off <<= 1) {
            s  += __shfl_xor(s, off);
            s2 += __shfl_xor(s2, off);
        }
        const double mean = s * (1.0 / 128.0);
        double var = fma(mean, -mean, s2 * (1.0 / 128.0));
        var = var < 0.0 ? 0.0 : var;
        const double v4 = 4.0 * var;   // (a-mean)^2 > 4*var  <=>  outlier (sqrt-free)

        // ---- classify + group maxima ----
        bool o[8];
        float mi = 0.0f, mov = 0.0f;
        #pragma unroll
        for (int i = 0; i < 8; ++i) {
            double dd = (double)a[i] - mean;
            o[i] = fma(dd, dd, -v4) > 0.0;
            float ab = fabsf(a[i]);
            mi  = fmaxf(mi,  o[i] ? 0.0f : ab);
            mov = fmaxf(mov, o[i] ? ab : 0.0f);
        }
        #pragma unroll
        for (int off = 1; off < 16; off <<= 1) {
            mi  = fmaxf(mi,  __shfl_xor(mi, off));
            mov = fmaxf(mov, __shfl_xor(mov, off));
        }

        // ---- shared exponents (exact integer math) ----
        int se_in = (mi == 0.0f) ? -126 : flog2_exact(mi);       // EMAX_IN = 0
        if (se_in < -127) se_in = -20;                           // SCALE_LO
        int se_out = ((mov == 0.0f) ? -126 : (flog2_exact(mov) + se_in)) - 8;
        if (se_out < -127) se_out = -20;
        const int d   = se_in - se_out;
        const int g_in = se_in - 4;                    // inlier grid exponent
        const float L_in  = ldexpf(31.0f, g_in);       // inlier clamp (exact)
        const float L_out = ldexpf(448.0f, -d);        // outlier clamp (exact)
        const int d3 = d + 3;

        // ---- unified quantize: one chain per element ----
        f32x4 r0, r1;
        #pragma unroll
        for (int i = 0; i < 8; ++i) {
            int e_a = (int)((__float_as_uint(a[i]) >> 23) & 0xFFu) - 127;
            int pe  = e_a + d;                 // = floor(log2|a * 2^d|) (exact)
            pe = pe < -6 ? -6 : pe;            // emin clamp
            int g = o[i] ? (pe - d3) : g_in;   // per-element grid exponent
            float r    = round_ref(ldexpf(a[i], -g));
            float outv = ldexpf(r, g);
            float L    = o[i] ? L_out : L_in;
            outv = fminf(fmaxf(outv, -L), L);
            if (i < 4) r0[i] = outv; else r1[i - 4] = outv;
        }

        __builtin_nontemporal_store(r0, &y[base]);
        __builtin_nontemporal_store(r1, &y[base + 16]);
    }
}

extern "C" void kernel_launch(void* const* d_in, const int* in_sizes, int n_in,
                              void* d_out, int out_size, void* d_ws, size_t ws_size,
                              hipStream_t stream) {
    const f32x4* x = (const f32x4*)d_in[0];
    f32x4* y = (f32x4*)d_out;
    int n = in_sizes[0];
    int ntask = n / 512;                 // 65536 wave-tasks (4 blocks each)
    int threads = 256;
    int waves_per_wg = threads / 64;
    int grid = 2048;
    int max_grid = (ntask + waves_per_wg - 1) / waves_per_wg;
    if (grid > max_grid) grid = max_grid;
    mxq_kernel<<<grid, threads, 0, stream>>>(x, y, ntask);
}